// Round 13
// baseline (106.776 us; speedup 1.0000x reference)
//
#include <hip/hip_runtime.h>
#include <math.h>

// DILATE / soft-DTW — round 13: SINGLE WAVE PER PROBLEM, ZERO BARRIERS.
// r12 post-mortem: the 3-wave phased skeleton stalls ~3x over issue
// (phase duty 64%, 22 barrier skews) and resisted 6 rounds of scheduling
// fixes. This round removes the skeleton: 512 blocks x 64 threads, one
// wave owns the whole 160x160 DP — lane L carries rows 3L+1..3L+3,
// rolling anti-diagonals live in registers, the ONLY cross-lane traffic
// is 2 DPP shifts/step (R and Rdot, lane0 border injected via DPP
// old-operand). No __syncthreads / rings / phases at all; 3 independent
// cells/lane/step give the ILP that hides chain latency.
// Math identical to r12 (proven): C2-domain carry (R*C2; GLN2*C2==1),
// subtract-form exp2 args (r5 NaN rule), forward-mode AD for the temporal
// term (r11: Rdot = Omega + w·Rdot preds), softmin weights reused.
// Left-border correctness: per-cell gate cur = act ? r : BIGC2 (r2-style);
// gated-BIG preds zero the weights, annihilating pre-valid Rdot garbage.
// Upper-triangle (j>160) garbage never feeds j<=160 cells (j monotone).
// P in 4-replica zero-padded LDS, 5x ds_read_b128 per 16-step chunk.

#define NN     160
#define BC_TOT 512
#define B_SZ   64
#define C_SZ   8
#define BIGC2  1e12f              // border sentinel in C2 domain
#define SC2    12.01122405f       // sqrt(C2), C2 = 144.269504089
#define GLN2   0.0069314718056f   // gamma*ln2 == 1/C2
#define KPH    16
#define NCHUNK 20                 // 320 steps, d = 2..321 (last is pad)

__device__ __forceinline__ float fexp2(float x) {
#if __has_builtin(__builtin_amdgcn_exp2f)
    return __builtin_amdgcn_exp2f(x);
#else
    return exp2f(x);
#endif
}
__device__ __forceinline__ float flog2(float x) {
#if __has_builtin(__builtin_amdgcn_logf)
    return __builtin_amdgcn_logf(x);
#else
    return log2f(x);
#endif
}
__device__ __forceinline__ float frcp(float x) {
#if __has_builtin(__builtin_amdgcn_rcpf)
    return __builtin_amdgcn_rcpf(x);
#else
    return 1.0f / x;
#endif
}
// lane i <- lane i-1; lane 0 <- old's lane-0 value (bound_ctrl=false).
__device__ __forceinline__ float dpp_up1_inj(float old, float x) {
    int oi = __builtin_bit_cast(int, old);
    int xi = __builtin_bit_cast(int, x);
    return __builtin_bit_cast(float,
        __builtin_amdgcn_update_dpp(oi, xi, 0x138, 0xF, 0xF, false)); // wave_shr1
}

__global__ __launch_bounds__(64, 1)
void dtw_fwd_kernel(const float* __restrict__ input,
                    const float* __restrict__ target,
                    float* __restrict__ sdtw,    // BC_TOT: R[N,N]
                    float* __restrict__ wlt)     // BC_TOT: Rdot[N,N]/N^2
{
    const int k    = blockIdx.x;
    const int lane = threadIdx.x;           // 0..63; rows 3L+1..3L+3

    __shared__ __align__(16) float Pp[4][520];  // replica s: Pp[s][y]=V(y+s)*SC2

    const float* tg = target + (size_t)k * NN;
    const float* pg = input  + (size_t)k * NN;
    // V(z) = P[z-192] for z in [192,352), else 0 (pre-scaled by sqrt(C2))
    for (int x = lane; x < 520; x += 64) {
        #pragma unroll
        for (int s = 0; s < 4; ++s) {
            const int v = x + s - 192;
            Pp[s][x] = ((unsigned)v < (unsigned)NN) ? pg[v] * SC2 : 0.0f;
        }
    }
    float tr[3];                            // T[i-1]*SC2 for rows i=3L+1+s
    #pragma unroll
    for (int u = 0; u < 3; ++u) {
        int idx = 3 * lane + u;
        idx = (idx > NN - 1) ? NN - 1 : idx;    // clamped (idle-lane safe)
        tr[u] = tg[idx] * SC2;
    }
    __syncthreads();   // one wave: ordering formality, executed once

    // rolling state (C2 domain): p1 = diag d-1, p2 = diag d-2 for own rows;
    // b1/b2 = row 3L boundary at d-1/d-2 (from lane-1 slot 2 via DPP).
    // Dual (Rdot): g1/g2, gb1/gb2. Borders: R=BIG, Rdot=0.
    float p1[3], p2[3], g1[3], g2[3];
    #pragma unroll
    for (int s = 0; s < 3; ++s) { p1[s] = BIGC2; p2[s] = BIGC2; g1[s] = 0.f; g2[s] = 0.f; }
    float b1  = BIGC2;
    float b2  = (lane == 0) ? 0.0f : BIGC2;     // R[0][0] = 0 enters at d=2
    float gb1 = 0.0f, gb2 = 0.0f;
    const float bigR = BIGC2, zeroR = 0.0f;     // DPP injection constants

    float dj[3];                                // j - i per slot (at d=2)
    #pragma unroll
    for (int s = 0; s < 3; ++s) dj[s] = (float)(-(6 * lane + 2 * s));

    int dlo = 2;
    for (int c = 0; c < NCHUNK; ++c, dlo += KPH) {
        // P batch: pvv[x] = V(A0+x), x in [0,20); cell (s,u) uses pvv[u+2-s]
        float pvv[20];
        {
            const int A0 = 192 + dlo - 3 * lane - 4;   // in [1, 494]
            const int sA = A0 & 3;
            const float4* pq = (const float4*)&Pp[sA][A0 - sA];
            #pragma unroll
            for (int x = 0; x < 5; ++x) {
                const float4 v4 = pq[x];
                pvv[4 * x]     = v4.x; pvv[4 * x + 1] = v4.y;
                pvv[4 * x + 2] = v4.z; pvv[4 * x + 3] = v4.w;
            }
        }
        #pragma unroll
        for (int u = 0; u < KPH; ++u) {
            const int d = dlo + u;
            float cur[3], gcur[3];
            #pragma unroll
            for (int s = 0; s < 3; ++s) {
                const float a  = (s == 0) ? b2  : p2[s - 1];  // R[i-1][j-1]
                const float bu = (s == 0) ? b1  : p1[s - 1];  // R[i-1][j]
                const float cl = p1[s];                       // R[i][j-1]
                const float ga = (s == 0) ? gb2 : g2[s - 1];
                const float gu = (s == 0) ? gb1 : g1[s - 1];
                const float gl = g1[s];
                const float mn = fminf(a, fminf(bu, cl));
                // SUBTRACT form mandatory (r5): exact 0 at min, never inf.
                const float ed = fexp2(mn - a);
                const float ev = fexp2(mn - bu);
                const float eh = fexp2(mn - cl);
                const float ss = ed + ev + eh;                // >= 1
                const float rs = frcp(ss);
                const float dtS = tr[s] - pvv[u + 2 - s];
                const float rC2 = __builtin_fmaf(dtS, dtS, mn) - flog2(ss);
                // gate ONLY the left border (j<1): pre-valid cells must
                // publish BIG so successors see true borders (r2 lesson).
                const bool act = d >= (3 * lane + s + 2);     // j >= 1
                cur[s] = act ? rC2 : BIGC2;
                const float num = __builtin_fmaf(ed, ga,
                                  __builtin_fmaf(ev, gu, eh * gl));
                gcur[s] = __builtin_fmaf(num, rs, dj[s] * dj[s]);
                dj[s] += 1.0f;
            }
            b2  = b1;  b1  = dpp_up1_inj(bigR,  cur[2]);   // lane0 <- BIG
            gb2 = gb1; gb1 = dpp_up1_inj(zeroR, gcur[2]);  // lane0 <- 0
            #pragma unroll
            for (int s = 0; s < 3; ++s) {
                p2[s] = p1[s]; p1[s] = cur[s];
                g2[s] = g1[s]; g1[s] = gcur[s];
            }
        }
    }
    // after final step p1 = diag 321 (pad), p2 = diag 320; row 160 = lane 53 s=0
    if (lane == 53) {
        sdtw[k] = p2[0] * GLN2;                 // back to normal domain
        wlt[k]  = g2[0] * (1.0f / (NN * NN));
    }
}

// final reduction: per-batch means + scalar loss. One wave (64 threads = B).
__global__ __launch_bounds__(64)
void finalize_kernel(const float* __restrict__ sdtw,
                     const float* __restrict__ wlt,
                     float* __restrict__ out)
{
    const int b = threadIdx.x;   // 0..63
    float ls = 0.0f, lt = 0.0f;
    #pragma unroll
    for (int c = 0; c < C_SZ; ++c) {
        ls += sdtw[b * C_SZ + c];
        lt += wlt[b * C_SZ + c];
    }
    ls *= (1.0f / C_SZ);
    lt *= (1.0f / C_SZ);
    out[1 + b]        = ls;
    out[1 + B_SZ + b] = lt;
    float v = 0.5f * ls + 0.5f * lt;
    #pragma unroll
    for (int o = 32; o > 0; o >>= 1) v += __shfl_down(v, o);
    if (b == 0) out[0] = v * (1.0f / B_SZ);
}

extern "C" void kernel_launch(void* const* d_in, const int* in_sizes, int n_in,
                              void* d_out, int out_size, void* d_ws, size_t ws_size,
                              hipStream_t stream) {
    const float* input  = (const float*)d_in[0];
    const float* target = (const float*)d_in[1];
    float* out = (float*)d_out;   // 129 floats

    float* sdtw = (float*)d_ws;                 // 512 floats
    float* wlt  = sdtw + BC_TOT;                // 512 floats

    dtw_fwd_kernel<<<BC_TOT, 64, 0, stream>>>(input, target, sdtw, wlt);
    finalize_kernel<<<1, 64, 0, stream>>>(sdtw, wlt, out);
}

// Round 14
// 97.268 us; speedup vs baseline: 1.0977x; 1.0977x over previous
//
#include <hip/hip_runtime.h>
#include <math.h>

// DILATE / soft-DTW — round 14: r12 champion + KPH=32 (half the barriers)
// + fused finalize (single dispatch, last-block reduction).
// r13 post-mortem: 1 wave/problem caps the machine at 512 waves for 1024
// SIMDs — r12's 3-wave phased pipeline (1536 waves, 6/CU) stays the right
// shape. This round: (1) KPH 16->32: NPHASE 22->12, chunk windows align
// exactly (64=2*32; active chunks 7/7/6); bigger register batches are free
// (occupancy is grid-capped, not VGPR-capped). (2) finalize fused via
// per-block done-flags + agent-scope atomics; block 511 spins (all 512
// blocks co-resident at 6 waves/CU) then reduces. Spin condition is
// `flag != 1` — correct whether ws is poisoned 0xAA or zeroed.
// Math unchanged from r12 (proven, absmax 0): C2-domain carry, DPP ring
// injection, merged (rC2,rdot) float2 ring, forward-mode AD dual,
// subtract-form exp2 args (mandatory — r5 NaN post-mortem), no per-cell
// gates (BIG-garbage drift << 1e12 keeps border semantics — r12/r13 lesson).

#define NN     160
#define BC_TOT 512
#define B_SZ   64
#define C_SZ   8
#define BIGC2  1e12f              // border sentinel in C2 domain
#define SC2    12.01122405f       // sqrt(C2), C2 = 144.269504089
#define GLN2   0.0069314718056f   // gamma*ln2 == 1/C2
#define KPH    32
#define NCHUNK 10                 // 320 diag-steps (incl. 1 pad), d=2..321
#define NPHASE 12                 // NCHUNK + 2 pipeline fill
#define RSZ    328                // linear ring slots (reads up to 321)

__device__ __forceinline__ float fexp2(float x) {
#if __has_builtin(__builtin_amdgcn_exp2f)
    return __builtin_amdgcn_exp2f(x);
#else
    return exp2f(x);
#endif
}
__device__ __forceinline__ float flog2(float x) {
#if __has_builtin(__builtin_amdgcn_logf)
    return __builtin_amdgcn_logf(x);
#else
    return log2f(x);
#endif
}
__device__ __forceinline__ float frcp(float x) {
#if __has_builtin(__builtin_amdgcn_rcpf)
    return __builtin_amdgcn_rcpf(x);
#else
    return 1.0f / x;
#endif
}
// lane i <- lane i-1; lane 0 <- old's value (bound_ctrl=false). Scan idiom.
__device__ __forceinline__ float dpp_up1_inj(float old, float x) {
    int oi = __builtin_bit_cast(int, old);
    int xi = __builtin_bit_cast(int, x);
    return __builtin_bit_cast(float,
        __builtin_amdgcn_update_dpp(oi, xi, 0x138, 0xF, 0xF, false)); // wave_shr1
}
// LDS-only barrier (no vmcnt drain). 0xC07F = vmcnt(63) expcnt(7) lgkmcnt(0).
__device__ __forceinline__ void barrier_lds() {
    __asm__ __volatile__("" ::: "memory");
    __builtin_amdgcn_s_waitcnt(0xC07F);
    __builtin_amdgcn_s_barrier();
    __asm__ __volatile__("" ::: "memory");
}

__global__ __launch_bounds__(192)
void dtw_fwd_kernel(const float* __restrict__ input,
                    const float* __restrict__ target,
                    float* __restrict__ sdtw,     // BC_TOT: R[N,N]
                    float* __restrict__ wlt,      // BC_TOT: Rdot[N,N]/N^2
                    unsigned* __restrict__ flags, // BC_TOT done-flags
                    float* __restrict__ out)      // 129 outputs
{
    const int k    = blockIdx.x;
    const int tid  = threadIdx.x;
    const int w    = tid >> 6;
    const int lane = tid & 63;
    const bool rowok = (tid < NN);

    __shared__ __align__(16) float  Pp[4][520];  // replica s: Pp[s][y]=V(y+s)*SC2
    __shared__ __align__(16) float2 bRG[2][RSZ]; // ring: (rC2, rdot) @ slot=diag

    const float* tg = target + (size_t)k * NN;
    const float* pg = input  + (size_t)k * NN;
    // V(z) = P[z-192]*SC2 for z in [192,352), else 0
    for (int x = tid; x < 520; x += 192) {
        #pragma unroll
        for (int s = 0; s < 4; ++s) {
            const int v = x + s - 192;
            Pp[s][x] = ((unsigned)v < (unsigned)NN) ? pg[v] * SC2 : 0.0f;
        }
    }
    for (int x = tid; x < 2 * RSZ; x += 192) {
        float2 z; z.x = BIGC2; z.y = 0.0f;   // unwritten slot == true border
        ((float2*)bRG)[x] = z;
    }
    const float trS = rowok ? tg[tid] * SC2 : 0.0f;
    barrier_lds();

    const bool isL0    = (lane == 0);
    const bool isL63p  = (lane == 63) && (w < 2);
    const bool useRing = (w > 0);
    const int  ti2     = 2 * (tid + 1);          // 2*i

    // Wave w active chunks: [2w, min(9, 2w+6)] — windows align (64 = 2*KPH).
    const int cLoF = 2 * w;
    const int cHiF = (2 * w + 6 < NCHUNK - 1) ? 2 * w + 6 : NCHUNK - 1;

    float r1c2 = BIGC2, u1c2 = BIGC2, u2c2 = BIGC2;
    float s1 = 0.0f, v1 = 0.0f, v2 = 0.0f;

    for (int t = 0; t < NPHASE; ++t) {
        const int c = t - w;
        if (c >= cLoF && c <= cHiF) {
            const int dlo = 2 + c * KPH;
            // ring window slots [dlo-2, dlo+31] (34): 17 aligned b128 reads
            float rgx[KPH + 2], rgd[KPH + 2];
            if (useRing) {
                const float4* q = (const float4*)&bRG[w - 1][dlo - 2];
                #pragma unroll
                for (int x = 0; x < 17; ++x) {
                    const float4 v4 = q[x];
                    rgx[2 * x]     = v4.x; rgd[2 * x]     = v4.y;
                    rgx[2 * x + 1] = v4.z; rgd[2 * x + 1] = v4.w;
                }
            } else {
                #pragma unroll
                for (int x = 0; x < KPH + 2; ++x) { rgx[x] = BIGC2; rgd[x] = 0.0f; }
                if (c == 0) rgx[0] = 0.0f;       // R[0][0] = 0 seed at d=2
            }
            // P window (pre-scaled): pvvS(u) = V(A+u), aligned replica
            float pvvS[KPH];
            {
                const int A  = 192 - tid + KPH * c;
                const int sA = A & 3;
                const float4* pq = (const float4*)&Pp[sA][A - sA];
                #pragma unroll
                for (int x = 0; x < KPH / 4; ++x) {
                    const float4 p4 = pq[x];
                    pvvS[4 * x]     = p4.x; pvvS[4 * x + 1] = p4.y;
                    pvvS[4 * x + 2] = p4.z; pvvS[4 * x + 3] = p4.w;
                }
            }
            if (c == cLoF) {     // one-time boundary injection (first chunk)
                u1c2 = isL0 ? rgx[1] : BIGC2;
                u2c2 = isL0 ? rgx[0] : BIGC2;
                v1   = isL0 ? rgd[1] : 0.0f;
                v2   = isL0 ? rgd[0] : 0.0f;
            }
            float djf = (float)(dlo - ti2);      // j - i at u=0
            #pragma unroll
            for (int u = 0; u < KPH; ++u) {
                const int d = dlo + u;           // d=321 pad step: harmless
                const float vdC = u2c2;          // R_c2[i-1][j-1]
                const float vuC = u1c2;          // R_c2[i-1][j]
                const float vlC = r1c2;          // R_c2[i][j-1]
                const float gd = v2, gu = v1, gl = s1;
                const float mnC = fminf(vdC, fminf(vuC, vlC));
                // SUBTRACT form mandatory (r5): exact 0 at min, always <= 0.
                const float ed = fexp2(mnC - vdC);
                const float ev = fexp2(mnC - vuC);
                const float eh = fexp2(mnC - vlC);
                const float ss = ed + ev + eh;   // >= 1
                const float rs = frcp(ss);
                const float dtS = trS - pvvS[u];
                const float rC2 = __builtin_fmaf(dtS, dtS, mnC) - flog2(ss);
                const float num = __builtin_fmaf(ed, gd,
                                  __builtin_fmaf(ev, gu, eh * gl));
                const float rdot = __builtin_fmaf(num, rs, djf * djf);
                if (isL63p) {                    // single b64 publish
                    float2 pub; pub.x = rC2; pub.y = rdot;
                    bRG[w][d] = pub;
                }
                if (d == 2 * NN) {
                    if (tid == NN - 1) {         // cell (160,160)
                        __hip_atomic_store(&sdtw[k], rC2 * GLN2,
                            __ATOMIC_RELAXED, __HIP_MEMORY_SCOPE_AGENT);
                        __hip_atomic_store(&wlt[k], rdot * (1.0f / (NN * NN)),
                            __ATOMIC_RELAXED, __HIP_MEMORY_SCOPE_AGENT);
                    }
                }
                u2c2 = u1c2;
                u1c2 = dpp_up1_inj(rgx[u + 2], rC2);   // lane0 <- ring slot d
                v2 = v1;
                v1 = dpp_up1_inj(rgd[u + 2], rdot);
                r1c2 = rC2;
                s1   = rdot;
                djf += 1.0f;
            }
        }
        barrier_lds();
    }

    // -------- fused finalize: publish done-flag; last block reduces --------
    __syncthreads();   // full barrier: drains the global stores (once)
    if (tid == 0)
        __hip_atomic_store(&flags[k], 1u, __ATOMIC_RELEASE,
                           __HIP_MEMORY_SCOPE_AGENT);
    if (k == BC_TOT - 1 && tid < B_SZ) {
        // all 512 blocks are co-resident (6 waves/CU) => spin is safe.
        // condition `!= 1` is init-agnostic (0xAA poison or zero).
        #pragma unroll 1
        for (int c = 0; c < C_SZ; ++c) {
            while (__hip_atomic_load(&flags[tid * C_SZ + c], __ATOMIC_ACQUIRE,
                                     __HIP_MEMORY_SCOPE_AGENT) != 1u)
                __builtin_amdgcn_s_sleep(8);
        }
        float ls = 0.0f, lt = 0.0f;
        #pragma unroll
        for (int c = 0; c < C_SZ; ++c) {
            ls += __hip_atomic_load(&sdtw[tid * C_SZ + c], __ATOMIC_RELAXED,
                                    __HIP_MEMORY_SCOPE_AGENT);
            lt += __hip_atomic_load(&wlt[tid * C_SZ + c], __ATOMIC_RELAXED,
                                    __HIP_MEMORY_SCOPE_AGENT);
        }
        ls *= (1.0f / C_SZ);
        lt *= (1.0f / C_SZ);
        out[1 + tid]        = ls;   // loss_shape
        out[1 + B_SZ + tid] = lt;   // loss_temporal
        float v = 0.5f * ls + 0.5f * lt;
        #pragma unroll
        for (int o = 32; o > 0; o >>= 1) v += __shfl_down(v, o);
        if (tid == 0) out[0] = v * (1.0f / B_SZ);
    }
}

extern "C" void kernel_launch(void* const* d_in, const int* in_sizes, int n_in,
                              void* d_out, int out_size, void* d_ws, size_t ws_size,
                              hipStream_t stream) {
    const float* input  = (const float*)d_in[0];
    const float* target = (const float*)d_in[1];
    float* out = (float*)d_out;   // 129 floats

    float*    sdtw  = (float*)d_ws;                  // 512
    float*    wlt   = sdtw + BC_TOT;                 // 512
    unsigned* flags = (unsigned*)(wlt + BC_TOT);     // 512

    dtw_fwd_kernel<<<BC_TOT, 192, 0, stream>>>(input, target, sdtw, wlt,
                                               flags, out);
}